// Round 1
// baseline (891.810 us; speedup 1.0000x reference)
//
#include <hip/hip_runtime.h>
#include <math.h>

// GCN 3-layer: h = relu(Agg(x@W1)+b1); h = relu(Agg(h@W2)+b2); out = Agg(h@W3)+b3
// Agg[i] = dinv[i]^2 * g[i] + sum_{e: dst=i} dinv[src]*dinv[i] * g[src]
// dinv = rsqrt(in_deg + 1)   (self-loop included)

#define N_NODES 100000
#define N_EDGES 1600000

// ---------------- preprocessing ----------------

__global__ __launch_bounds__(256) void k_zero_int(int* __restrict__ p, int n) {
    int i = blockIdx.x * 256 + threadIdx.x;
    if (i < n) p[i] = 0;
}

__global__ __launch_bounds__(256) void k_count(const int* __restrict__ dst, int* __restrict__ cnt, int E) {
    int e = blockIdx.x * 256 + threadIdx.x;
    if (e < E) atomicAdd(&cnt[dst[e]], 1);
}

// per-256-block exclusive scan + block sums
__global__ __launch_bounds__(256) void k_scan_block(const int* __restrict__ cnt, int* __restrict__ excl,
                                                    int* __restrict__ bsum, int n) {
    __shared__ int s[256];
    int i = blockIdx.x * 256 + threadIdx.x;
    int v = (i < n) ? cnt[i] : 0;
    s[threadIdx.x] = v;
    __syncthreads();
    #pragma unroll
    for (int off = 1; off < 256; off <<= 1) {
        int t = (threadIdx.x >= (unsigned)off) ? s[threadIdx.x - off] : 0;
        __syncthreads();
        s[threadIdx.x] += t;
        __syncthreads();
    }
    if (i < n) excl[i] = s[threadIdx.x] - v;
    if (threadIdx.x == 255) bsum[blockIdx.x] = s[255];
}

// single-block exclusive scan over block sums (nb <= 512)
__global__ __launch_bounds__(512) void k_scan_partials(int* __restrict__ bsum, int nb) {
    __shared__ int s[512];
    int tid = threadIdx.x;
    int v = (tid < nb) ? bsum[tid] : 0;
    s[tid] = v;
    __syncthreads();
    #pragma unroll
    for (int off = 1; off < 512; off <<= 1) {
        int t = (tid >= (unsigned)off) ? s[tid - off] : 0;
        __syncthreads();
        s[tid] += t;
        __syncthreads();
    }
    if (tid < nb) bsum[tid] = s[tid] - v;   // exclusive
}

__global__ __launch_bounds__(256) void k_finalize(const int* __restrict__ excl, const int* __restrict__ bsum,
                                                  const int* __restrict__ cnt, int* __restrict__ rowptr,
                                                  int* __restrict__ fill, float* __restrict__ dinv, int n) {
    int i = blockIdx.x * 256 + threadIdx.x;
    if (i < n) {
        int rp = excl[i] + bsum[i >> 8];
        rowptr[i] = rp;
        fill[i]   = rp;
        dinv[i]   = rsqrtf((float)(cnt[i] + 1));  // +1 self loop; always > 0
    }
}

__global__ __launch_bounds__(256) void k_fill_edges(const int* __restrict__ src, const int* __restrict__ dst,
                                                    const float* __restrict__ dinv, int* __restrict__ fill,
                                                    int* __restrict__ csr_src, float* __restrict__ csr_norm, int E) {
    int e = blockIdx.x * 256 + threadIdx.x;
    if (e < E) {
        int s = src[e], d = dst[e];
        int p = atomicAdd(&fill[d], 1);
        csr_src[p]  = s;
        csr_norm[p] = dinv[s] * dinv[d];
    }
}

// ---------------- f32 GEMM: Y[n,128] = X[n,K] @ W[K,128] ----------------
// BM=64, BN=128, BK=64, 256 threads, 8x4 micro-tile/thread.

template <int K>
__global__ __launch_bounds__(256) void k_gemm(const float* __restrict__ X, const float* __restrict__ W,
                                              float* __restrict__ Y, int n) {
    __shared__ float sX[64][64];    // 16 KB
    __shared__ float sW[64][128];   // 32 KB
    const int t   = threadIdx.x;
    const int row0 = blockIdx.x * 64;
    const int tn  = t & 31;   // cols 4*tn .. 4*tn+3
    const int tm  = t >> 5;   // rows 8*tm .. 8*tm+7

    float acc[8][4];
    #pragma unroll
    for (int i = 0; i < 8; ++i)
        #pragma unroll
        for (int j = 0; j < 4; ++j) acc[i][j] = 0.f;

    for (int kb = 0; kb < K; kb += 64) {
        // X tile: 64x64 floats = 1024 float4, 4 per thread
        #pragma unroll
        for (int i = 0; i < 4; ++i) {
            int f  = t + i * 256;
            int r  = f >> 4;        // /16 float4-per-row
            int c4 = f & 15;
            int gr = row0 + r;
            float4 v = make_float4(0.f, 0.f, 0.f, 0.f);
            if (gr < n) v = *(const float4*)&X[(size_t)gr * K + kb + c4 * 4];
            *(float4*)&sX[r][c4 * 4] = v;
        }
        // W tile: 64x128 floats = 2048 float4, 8 per thread
        #pragma unroll
        for (int i = 0; i < 8; ++i) {
            int f  = t + i * 256;
            int r  = f >> 5;        // /32 float4-per-row
            int c4 = f & 31;
            *(float4*)&sW[r][c4 * 4] = *(const float4*)&W[(size_t)(kb + r) * 128 + c4 * 4];
        }
        __syncthreads();

        #pragma unroll
        for (int k4 = 0; k4 < 64; k4 += 4) {
            float4 bv[4];
            #pragma unroll
            for (int kk = 0; kk < 4; ++kk) bv[kk] = *(const float4*)&sW[k4 + kk][tn * 4];
            #pragma unroll
            for (int i = 0; i < 8; ++i) {
                float4 av = *(const float4*)&sX[tm * 8 + i][k4];
                #pragma unroll
                for (int j = 0; j < 4; ++j) {
                    float b0 = ((const float*)&bv[0])[j];
                    float b1 = ((const float*)&bv[1])[j];
                    float b2 = ((const float*)&bv[2])[j];
                    float b3 = ((const float*)&bv[3])[j];
                    acc[i][j] = fmaf(av.x, b0, acc[i][j]);
                    acc[i][j] = fmaf(av.y, b1, acc[i][j]);
                    acc[i][j] = fmaf(av.z, b2, acc[i][j]);
                    acc[i][j] = fmaf(av.w, b3, acc[i][j]);
                }
            }
        }
        __syncthreads();
    }

    #pragma unroll
    for (int i = 0; i < 8; ++i) {
        int gr = row0 + tm * 8 + i;
        if (gr < n) {
            float4 v = make_float4(acc[i][0], acc[i][1], acc[i][2], acc[i][3]);
            *(float4*)&Y[(size_t)gr * 128 + tn * 4] = v;
        }
    }
}

// ---------------- aggregation (+ bias, + optional relu) ----------------
// one wave (64 lanes) per node; lane holds float2 of the 128-wide row.

template <bool RELU>
__global__ __launch_bounds__(256) void k_agg(const float* __restrict__ H, const int* __restrict__ rowptr,
                                             const int* __restrict__ cnt, const int* __restrict__ csr_src,
                                             const float* __restrict__ csr_norm, const float* __restrict__ dinv,
                                             const float* __restrict__ bias, float* __restrict__ out, int n) {
    int node = (int)((blockIdx.x * 256 + threadIdx.x) >> 6);
    if (node >= n) return;
    int lane = threadIdx.x & 63;

    const float2* __restrict__ H2 = (const float2*)H;
    float dv = dinv[node];
    float2 h = H2[node * 64 + lane];
    float w0 = dv * dv;
    float ax = w0 * h.x, ay = w0 * h.y;

    int c0 = rowptr[node];
    int cn = cnt[node];
    for (int e = 0; e < cn; ++e) {
        int   s = csr_src[c0 + e];
        float w = csr_norm[c0 + e];
        float2 hs = H2[s * 64 + lane];
        ax = fmaf(w, hs.x, ax);
        ay = fmaf(w, hs.y, ay);
    }

    float2 b = *(const float2*)&bias[lane * 2];
    ax += b.x;
    ay += b.y;
    if (RELU) {
        ax = fmaxf(ax, 0.f);
        ay = fmaxf(ay, 0.f);
    }
    float2 o;
    o.x = ax;
    o.y = ay;
    *(float2*)&out[(size_t)node * 128 + lane * 2] = o;
}

// ---------------- launch ----------------

extern "C" void kernel_launch(void* const* d_in, const int* in_sizes, int n_in,
                              void* d_out, int out_size, void* d_ws, size_t ws_size,
                              hipStream_t stream) {
    const float* x  = (const float*)d_in[0];
    const int*   ei = (const int*)d_in[1];
    const float* W1 = (const float*)d_in[2];
    const float* b1 = (const float*)d_in[3];
    const float* W2 = (const float*)d_in[4];
    const float* b2 = (const float*)d_in[5];
    const float* W3 = (const float*)d_in[6];
    const float* b3 = (const float*)d_in[7];
    float* out = (float*)d_out;

    const int N = N_NODES, E = N_EDGES;
    const int* src = ei;       // edge_index[0]
    const int* dst = ei + E;   // edge_index[1]

    char* w = (char*)d_ws;
    auto alloc = [&](size_t bytes) -> void* {
        void* p = (void*)w;
        w += (bytes + 255) & ~(size_t)255;
        return p;
    };
    int*   cnt      = (int*)alloc((size_t)N * 4);
    int*   excl     = (int*)alloc((size_t)N * 4);
    int*   bsum     = (int*)alloc(4096);
    int*   rowptr   = (int*)alloc((size_t)N * 4);
    int*   fill     = (int*)alloc((size_t)N * 4);
    float* dinv     = (float*)alloc((size_t)N * 4);
    int*   csr_src  = (int*)alloc((size_t)E * 4);
    float* csr_norm = (float*)alloc((size_t)E * 4);
    float* P        = (float*)alloc((size_t)N * 128 * 4);
    float* Q        = out;  // ping-pong through d_out; fully rewritten by final layer

    const int nbN = (N + 255) / 256;   // 391
    const int nbE = (E + 255) / 256;

    // CSR build
    k_zero_int<<<nbN, 256, 0, stream>>>(cnt, N);
    k_count<<<nbE, 256, 0, stream>>>(dst, cnt, E);
    k_scan_block<<<nbN, 256, 0, stream>>>(cnt, excl, bsum, N);
    k_scan_partials<<<1, 512, 0, stream>>>(bsum, nbN);
    k_finalize<<<nbN, 256, 0, stream>>>(excl, bsum, cnt, rowptr, fill, dinv, N);
    k_fill_edges<<<nbE, 256, 0, stream>>>(src, dst, dinv, fill, csr_src, csr_norm, E);

    const int gemm_grid = (N + 63) / 64;   // 1563
    const int agg_grid  = (N + 3) / 4;     // 25000 (4 waves/block, 1 node/wave)

    // layer 1
    k_gemm<256><<<gemm_grid, 256, 0, stream>>>(x, W1, P, N);
    k_agg<true><<<agg_grid, 256, 0, stream>>>(P, rowptr, cnt, csr_src, csr_norm, dinv, b1, Q, N);
    // layer 2
    k_gemm<128><<<gemm_grid, 256, 0, stream>>>(Q, W2, P, N);
    k_agg<true><<<agg_grid, 256, 0, stream>>>(P, rowptr, cnt, csr_src, csr_norm, dinv, b2, Q, N);
    // layer 3
    k_gemm<128><<<gemm_grid, 256, 0, stream>>>(Q, W3, P, N);
    k_agg<false><<<agg_grid, 256, 0, stream>>>(P, rowptr, cnt, csr_src, csr_norm, dinv, b3, out, N);
}

// Round 2
// 770.867 us; speedup vs baseline: 1.1569x; 1.1569x over previous
//
#include <hip/hip_runtime.h>
#include <math.h>

// GCN 3-layer: h = relu(Agg(x@W1)+b1); h = relu(Agg(h@W2)+b2); out = Agg(h@W3)+b3
// Agg[i] = dinv[i]^2 * g[i] + sum_{e: dst=i} dinv[src]*dinv[i] * g[src]
// dinv = rsqrt(in_deg + 1)   (self-loop included)

#define N_NODES 100000
#define N_EDGES 1600000

// ---------------- preprocessing ----------------

__global__ __launch_bounds__(256) void k_zero_int(int* __restrict__ p, int n) {
    int i = blockIdx.x * 256 + threadIdx.x;
    if (i < n) p[i] = 0;
}

__global__ __launch_bounds__(256) void k_count(const int* __restrict__ dst, int* __restrict__ cnt, int E) {
    int e = blockIdx.x * 256 + threadIdx.x;
    if (e < E) atomicAdd(&cnt[dst[e]], 1);
}

// per-256-block exclusive scan (over 4-padded counts) + block sums
__global__ __launch_bounds__(256) void k_scan_block(const int* __restrict__ cnt, int* __restrict__ excl,
                                                    int* __restrict__ bsum, int n) {
    __shared__ int s[256];
    int i = blockIdx.x * 256 + threadIdx.x;
    int v = (i < n) ? ((cnt[i] + 3) & ~3) : 0;   // padded segment length
    s[threadIdx.x] = v;
    __syncthreads();
    #pragma unroll
    for (int off = 1; off < 256; off <<= 1) {
        int t = (threadIdx.x >= (unsigned)off) ? s[threadIdx.x - off] : 0;
        __syncthreads();
        s[threadIdx.x] += t;
        __syncthreads();
    }
    if (i < n) excl[i] = s[threadIdx.x] - v;
    if (threadIdx.x == 255) bsum[blockIdx.x] = s[255];
}

// single-block exclusive scan over block sums (nb <= 512)
__global__ __launch_bounds__(512) void k_scan_partials(int* __restrict__ bsum, int nb) {
    __shared__ int s[512];
    int tid = threadIdx.x;
    int v = (tid < nb) ? bsum[tid] : 0;
    s[tid] = v;
    __syncthreads();
    #pragma unroll
    for (int off = 1; off < 512; off <<= 1) {
        int t = (tid >= (unsigned)off) ? s[tid - off] : 0;
        __syncthreads();
        s[tid] += t;
        __syncthreads();
    }
    if (tid < nb) bsum[tid] = s[tid] - v;   // exclusive
}

__global__ __launch_bounds__(256) void k_finalize(const int* __restrict__ excl, const int* __restrict__ bsum,
                                                  const int* __restrict__ cnt, int* __restrict__ rowptr,
                                                  int* __restrict__ fill, float* __restrict__ dinv, int n) {
    int i = blockIdx.x * 256 + threadIdx.x;
    if (i < n) {
        int rp = excl[i] + bsum[i >> 8];
        rowptr[i] = rp;     // 4-aligned (scan of multiples of 4)
        fill[i]   = rp;
        dinv[i]   = rsqrtf((float)(cnt[i] + 1));  // +1 self loop; always > 0
    }
}

// zero csr arrays so padding slots gather node 0 with weight 0
__global__ __launch_bounds__(256) void k_zero_csr(int* __restrict__ s, float* __restrict__ w, int n) {
    int i = blockIdx.x * 256 + threadIdx.x;
    if (i < n) { s[i] = 0; w[i] = 0.f; }
}

__global__ __launch_bounds__(256) void k_fill_edges(const int* __restrict__ src, const int* __restrict__ dst,
                                                    const float* __restrict__ dinv, int* __restrict__ fill,
                                                    int* __restrict__ csr_src, float* __restrict__ csr_norm, int E) {
    int e = blockIdx.x * 256 + threadIdx.x;
    if (e < E) {
        int s = src[e], d = dst[e];
        int p = atomicAdd(&fill[d], 1);
        csr_src[p]  = s;
        csr_norm[p] = dinv[s] * dinv[d];
    }
}

// ---------------- f32 GEMM: Y[n,128] = X[n,K] @ W[K,128] ----------------
// BM=64, BN=128, BK=64, 256 threads, 8x4 micro-tile/thread.

template <int K>
__global__ __launch_bounds__(256) void k_gemm(const float* __restrict__ X, const float* __restrict__ W,
                                              float* __restrict__ Y, int n) {
    __shared__ float sX[64][64];    // 16 KB
    __shared__ float sW[64][128];   // 32 KB
    const int t   = threadIdx.x;
    const int row0 = blockIdx.x * 64;
    const int tn  = t & 31;   // cols 4*tn .. 4*tn+3
    const int tm  = t >> 5;   // rows 8*tm .. 8*tm+7

    float acc[8][4];
    #pragma unroll
    for (int i = 0; i < 8; ++i)
        #pragma unroll
        for (int j = 0; j < 4; ++j) acc[i][j] = 0.f;

    for (int kb = 0; kb < K; kb += 64) {
        // X tile: 64x64 floats = 1024 float4, 4 per thread
        #pragma unroll
        for (int i = 0; i < 4; ++i) {
            int f  = t + i * 256;
            int r  = f >> 4;        // /16 float4-per-row
            int c4 = f & 15;
            int gr = row0 + r;
            float4 v = make_float4(0.f, 0.f, 0.f, 0.f);
            if (gr < n) v = *(const float4*)&X[(size_t)gr * K + kb + c4 * 4];
            *(float4*)&sX[r][c4 * 4] = v;
        }
        // W tile: 64x128 floats = 2048 float4, 8 per thread
        #pragma unroll
        for (int i = 0; i < 8; ++i) {
            int f  = t + i * 256;
            int r  = f >> 5;        // /32 float4-per-row
            int c4 = f & 31;
            *(float4*)&sW[r][c4 * 4] = *(const float4*)&W[(size_t)(kb + r) * 128 + c4 * 4];
        }
        __syncthreads();

        #pragma unroll
        for (int k4 = 0; k4 < 64; k4 += 4) {
            float4 bv[4];
            #pragma unroll
            for (int kk = 0; kk < 4; ++kk) bv[kk] = *(const float4*)&sW[k4 + kk][tn * 4];
            #pragma unroll
            for (int i = 0; i < 8; ++i) {
                float4 av = *(const float4*)&sX[tm * 8 + i][k4];
                #pragma unroll
                for (int j = 0; j < 4; ++j) {
                    float b0 = ((const float*)&bv[0])[j];
                    float b1 = ((const float*)&bv[1])[j];
                    float b2 = ((const float*)&bv[2])[j];
                    float b3 = ((const float*)&bv[3])[j];
                    acc[i][j] = fmaf(av.x, b0, acc[i][j]);
                    acc[i][j] = fmaf(av.y, b1, acc[i][j]);
                    acc[i][j] = fmaf(av.z, b2, acc[i][j]);
                    acc[i][j] = fmaf(av.w, b3, acc[i][j]);
                }
            }
        }
        __syncthreads();
    }

    #pragma unroll
    for (int i = 0; i < 8; ++i) {
        int gr = row0 + tm * 8 + i;
        if (gr < n) {
            float4 v = make_float4(acc[i][0], acc[i][1], acc[i][2], acc[i][3]);
            *(float4*)&Y[(size_t)gr * 128 + tn * 4] = v;
        }
    }
}

// ---------------- aggregation (+ bias, + optional relu) ----------------
// one wave (64 lanes) per node, grid-stride over nodes; lane holds float2
// of the 128-wide row. CSR segments are 4-padded & 16B-aligned so each
// iteration reads 4 edges (int4+float4, wave-uniform) and issues 4
// independent 512B row gathers -> deep MLP instead of 1 dependent chain.

template <bool RELU>
__global__ __launch_bounds__(256) void k_agg(const float* __restrict__ H, const int* __restrict__ rowptr,
                                             const int* __restrict__ cnt, const int* __restrict__ csr_src,
                                             const float* __restrict__ csr_norm, const float* __restrict__ dinv,
                                             const float* __restrict__ bias, float* __restrict__ out, int n) {
    const int lane  = threadIdx.x & 63;
    const int wave0 = (int)((blockIdx.x * 256 + threadIdx.x) >> 6);
    const int nwave = (int)((gridDim.x * 256) >> 6);
    const float2* __restrict__ H2 = (const float2*)H;
    const float2 b = *(const float2*)&bias[lane * 2];

    for (int node = wave0; node < n; node += nwave) {
        float dv = dinv[node];
        float2 h = H2[(size_t)node * 64 + lane];
        float w0 = dv * dv;
        float ax = fmaf(w0, h.x, b.x);
        float ay = fmaf(w0, h.y, b.y);

        const int c0 = rowptr[node];
        const int cn = cnt[node];
        #pragma unroll 2
        for (int e4 = 0; e4 < cn; e4 += 4) {
            int4   ss = *(const int4*)  &csr_src [c0 + e4];
            float4 ww = *(const float4*)&csr_norm[c0 + e4];
            float2 h0 = H2[(size_t)ss.x * 64 + lane];
            float2 h1 = H2[(size_t)ss.y * 64 + lane];
            float2 h2 = H2[(size_t)ss.z * 64 + lane];
            float2 h3 = H2[(size_t)ss.w * 64 + lane];
            ax = fmaf(ww.x, h0.x, ax); ay = fmaf(ww.x, h0.y, ay);
            ax = fmaf(ww.y, h1.x, ax); ay = fmaf(ww.y, h1.y, ay);
            ax = fmaf(ww.z, h2.x, ax); ay = fmaf(ww.z, h2.y, ay);
            ax = fmaf(ww.w, h3.x, ax); ay = fmaf(ww.w, h3.y, ay);
        }

        if (RELU) {
            ax = fmaxf(ax, 0.f);
            ay = fmaxf(ay, 0.f);
        }
        *(float2*)&out[(size_t)node * 128 + lane * 2] = make_float2(ax, ay);
    }
}

// ---------------- launch ----------------

extern "C" void kernel_launch(void* const* d_in, const int* in_sizes, int n_in,
                              void* d_out, int out_size, void* d_ws, size_t ws_size,
                              hipStream_t stream) {
    const float* x  = (const float*)d_in[0];
    const int*   ei = (const int*)d_in[1];
    const float* W1 = (const float*)d_in[2];
    const float* b1 = (const float*)d_in[3];
    const float* W2 = (const float*)d_in[4];
    const float* b2 = (const float*)d_in[5];
    const float* W3 = (const float*)d_in[6];
    const float* b3 = (const float*)d_in[7];
    float* out = (float*)d_out;

    const int N = N_NODES, E = N_EDGES;
    const int EP = E + 3 * N + 64;   // padded CSR capacity
    const int* src = ei;       // edge_index[0]
    const int* dst = ei + E;   // edge_index[1]

    char* w = (char*)d_ws;
    auto alloc = [&](size_t bytes) -> void* {
        void* p = (void*)w;
        w += (bytes + 255) & ~(size_t)255;
        return p;
    };
    int*   cnt      = (int*)alloc((size_t)N * 4);
    int*   excl     = (int*)alloc((size_t)N * 4);
    int*   bsum     = (int*)alloc(4096);
    int*   rowptr   = (int*)alloc((size_t)N * 4);
    int*   fill     = (int*)alloc((size_t)N * 4);
    float* dinv     = (float*)alloc((size_t)N * 4);
    int*   csr_src  = (int*)alloc((size_t)EP * 4);
    float* csr_norm = (float*)alloc((size_t)EP * 4);
    float* P        = (float*)alloc((size_t)N * 128 * 4);
    float* Q        = out;  // ping-pong through d_out; fully rewritten by final layer

    const int nbN = (N + 255) / 256;   // 391
    const int nbE = (E + 255) / 256;
    const int nbP = (EP + 255) / 256;

    // CSR build (4-padded segments, zero-filled padding)
    k_zero_int<<<nbN, 256, 0, stream>>>(cnt, N);
    k_count<<<nbE, 256, 0, stream>>>(dst, cnt, E);
    k_scan_block<<<nbN, 256, 0, stream>>>(cnt, excl, bsum, N);
    k_scan_partials<<<1, 512, 0, stream>>>(bsum, nbN);
    k_finalize<<<nbN, 256, 0, stream>>>(excl, bsum, cnt, rowptr, fill, dinv, N);
    k_zero_csr<<<nbP, 256, 0, stream>>>(csr_src, csr_norm, EP);
    k_fill_edges<<<nbE, 256, 0, stream>>>(src, dst, dinv, fill, csr_src, csr_norm, E);

    const int gemm_grid = (N + 63) / 64;   // 1563
    const int agg_grid  = 2048;            // grid-stride, 4 waves/block

    // layer 1
    k_gemm<256><<<gemm_grid, 256, 0, stream>>>(x, W1, P, N);
    k_agg<true><<<agg_grid, 256, 0, stream>>>(P, rowptr, cnt, csr_src, csr_norm, dinv, b1, Q, N);
    // layer 2
    k_gemm<128><<<gemm_grid, 256, 0, stream>>>(Q, W2, P, N);
    k_agg<true><<<agg_grid, 256, 0, stream>>>(P, rowptr, cnt, csr_src, csr_norm, dinv, b2, Q, N);
    // layer 3
    k_gemm<128><<<gemm_grid, 256, 0, stream>>>(Q, W3, P, N);
    k_agg<false><<<agg_grid, 256, 0, stream>>>(P, rowptr, cnt, csr_src, csr_norm, dinv, b3, out, N);
}

// Round 3
// 724.476 us; speedup vs baseline: 1.2310x; 1.0640x over previous
//
#include <hip/hip_runtime.h>
#include <math.h>

// GCN 3-layer: h = relu(Agg(x@W1)+b1); h = relu(Agg(h@W2)+b2); out = Agg(h@W3)+b3
// Agg[i] = dinv[i]^2 * g[i] + sum_{e: dst=i} dinv[src]*dinv[i] * g[src]
// dinv = rsqrt(in_deg + 1)   (self-loop included)

#define N_NODES 100000
#define N_EDGES 1600000

// ---------------- preprocessing ----------------

__global__ __launch_bounds__(256) void k_zero_int(int* __restrict__ p, int n) {
    int i = blockIdx.x * 256 + threadIdx.x;
    if (i < n) p[i] = 0;
}

__global__ __launch_bounds__(256) void k_count(const int* __restrict__ dst, int* __restrict__ cnt, int E) {
    int e = blockIdx.x * 256 + threadIdx.x;
    if (e < E) atomicAdd(&cnt[dst[e]], 1);
}

// per-256-block exclusive scan (over 8-padded counts) + block sums
__global__ __launch_bounds__(256) void k_scan_block(const int* __restrict__ cnt, int* __restrict__ excl,
                                                    int* __restrict__ bsum, int n) {
    __shared__ int s[256];
    int i = blockIdx.x * 256 + threadIdx.x;
    int v = (i < n) ? ((cnt[i] + 7) & ~7) : 0;   // padded segment length
    s[threadIdx.x] = v;
    __syncthreads();
    #pragma unroll
    for (int off = 1; off < 256; off <<= 1) {
        int t = (threadIdx.x >= (unsigned)off) ? s[threadIdx.x - off] : 0;
        __syncthreads();
        s[threadIdx.x] += t;
        __syncthreads();
    }
    if (i < n) excl[i] = s[threadIdx.x] - v;
    if (threadIdx.x == 255) bsum[blockIdx.x] = s[255];
}

// single-block exclusive scan over block sums (nb <= 512)
__global__ __launch_bounds__(512) void k_scan_partials(int* __restrict__ bsum, int nb) {
    __shared__ int s[512];
    int tid = threadIdx.x;
    int v = (tid < nb) ? bsum[tid] : 0;
    s[tid] = v;
    __syncthreads();
    #pragma unroll
    for (int off = 1; off < 512; off <<= 1) {
        int t = (tid >= (unsigned)off) ? s[tid - off] : 0;
        __syncthreads();
        s[tid] += t;
        __syncthreads();
    }
    if (tid < nb) bsum[tid] = s[tid] - v;   // exclusive
}

__global__ __launch_bounds__(256) void k_finalize(const int* __restrict__ excl, const int* __restrict__ bsum,
                                                  const int* __restrict__ cnt, int* __restrict__ rowptr,
                                                  int* __restrict__ fill, float* __restrict__ dinv, int n) {
    int i = blockIdx.x * 256 + threadIdx.x;
    if (i < n) {
        int rp = excl[i] + bsum[i >> 8];
        rowptr[i] = rp;     // 8-aligned (scan of multiples of 8)
        fill[i]   = rp;
        dinv[i]   = rsqrtf((float)(cnt[i] + 1));  // +1 self loop; always > 0
    }
}

// zero paired csr so padding slots gather node 0 with weight 0
__global__ __launch_bounds__(256) void k_zero_csr(int2* __restrict__ csr, int n) {
    int i = blockIdx.x * 256 + threadIdx.x;
    if (i < n) csr[i] = make_int2(0, 0);
}

__global__ __launch_bounds__(256) void k_fill_edges(const int* __restrict__ src, const int* __restrict__ dst,
                                                    const float* __restrict__ dinv, int* __restrict__ fill,
                                                    int2* __restrict__ csr, int E) {
    int e = blockIdx.x * 256 + threadIdx.x;
    if (e < E) {
        int s = src[e], d = dst[e];
        int p = atomicAdd(&fill[d], 1);
        csr[p] = make_int2(s, __float_as_int(dinv[s] * dinv[d]));
    }
}

// ---------------- f32 GEMM: Y[n,128] = X[n,K] @ W[K,128] ----------------
// BM=64, BN=128, BK=32, 256 threads, 8x4 micro-tile/thread. LDS 24 KB -> 5-6 blocks/CU.

template <int K>
__global__ __launch_bounds__(256) void k_gemm(const float* __restrict__ X, const float* __restrict__ W,
                                              float* __restrict__ Y, int n) {
    __shared__ float sX[64][32];    // 8 KB
    __shared__ float sW[32][128];   // 16 KB
    const int t    = threadIdx.x;
    const int row0 = blockIdx.x * 64;
    const int tn   = t & 31;   // cols 4*tn .. 4*tn+3
    const int tm   = t >> 5;   // rows 8*tm .. 8*tm+7

    float acc[8][4];
    #pragma unroll
    for (int i = 0; i < 8; ++i)
        #pragma unroll
        for (int j = 0; j < 4; ++j) acc[i][j] = 0.f;

    for (int kb = 0; kb < K; kb += 32) {
        // X tile: 64x32 floats = 512 float4, 2 per thread
        #pragma unroll
        for (int i = 0; i < 2; ++i) {
            int f  = t + i * 256;
            int r  = f >> 3;        // /8 float4-per-row
            int c4 = f & 7;
            int gr = row0 + r;
            float4 v = make_float4(0.f, 0.f, 0.f, 0.f);
            if (gr < n) v = *(const float4*)&X[(size_t)gr * K + kb + c4 * 4];
            *(float4*)&sX[r][c4 * 4] = v;
        }
        // W tile: 32x128 floats = 1024 float4, 4 per thread
        #pragma unroll
        for (int i = 0; i < 4; ++i) {
            int f  = t + i * 256;
            int r  = f >> 5;        // /32 float4-per-row
            int c4 = f & 31;
            *(float4*)&sW[r][c4 * 4] = *(const float4*)&W[(size_t)(kb + r) * 128 + c4 * 4];
        }
        __syncthreads();

        #pragma unroll
        for (int k4 = 0; k4 < 32; k4 += 4) {
            float4 bv[4];
            #pragma unroll
            for (int kk = 0; kk < 4; ++kk) bv[kk] = *(const float4*)&sW[k4 + kk][tn * 4];
            #pragma unroll
            for (int i = 0; i < 8; ++i) {
                float4 av = *(const float4*)&sX[tm * 8 + i][k4];
                #pragma unroll
                for (int j = 0; j < 4; ++j) {
                    float b0 = ((const float*)&bv[0])[j];
                    float b1 = ((const float*)&bv[1])[j];
                    float b2 = ((const float*)&bv[2])[j];
                    float b3 = ((const float*)&bv[3])[j];
                    acc[i][j] = fmaf(av.x, b0, acc[i][j]);
                    acc[i][j] = fmaf(av.y, b1, acc[i][j]);
                    acc[i][j] = fmaf(av.z, b2, acc[i][j]);
                    acc[i][j] = fmaf(av.w, b3, acc[i][j]);
                }
            }
        }
        __syncthreads();
    }

    #pragma unroll
    for (int i = 0; i < 8; ++i) {
        int gr = row0 + tm * 8 + i;
        if (gr < n) {
            float4 v = make_float4(acc[i][0], acc[i][1], acc[i][2], acc[i][3]);
            *(float4*)&Y[(size_t)gr * 128 + tn * 4] = v;
        }
    }
}

// ---------------- aggregation (+ bias, + optional relu) ----------------
// one wave (64 lanes) per node, grid-stride; lane holds float2 of the
// 128-wide row. CSR segments are 8-padded, stored as interleaved
// (src, norm_bits) int2 pairs. Each iteration: 4 uniform int4 reads (64 B)
// + 8 independent 512 B row gathers in flight before any fma.

template <bool RELU>
__global__ __launch_bounds__(256) void k_agg(const float* __restrict__ H, const int* __restrict__ rowptr,
                                             const int* __restrict__ cnt, const int2* __restrict__ csr,
                                             const float* __restrict__ dinv, const float* __restrict__ bias,
                                             float* __restrict__ out, int n) {
    const int lane  = threadIdx.x & 63;
    const int wave0 = (int)((blockIdx.x * 256 + threadIdx.x) >> 6);
    const int nwave = (int)((gridDim.x * 256) >> 6);
    const float2* __restrict__ H2 = (const float2*)H;
    const float2 b = *(const float2*)&bias[lane * 2];

    for (int node = wave0; node < n; node += nwave) {
        float dv = dinv[node];
        float2 h = H2[(size_t)node * 64 + lane];
        float w0 = dv * dv;
        float ax = fmaf(w0, h.x, b.x);
        float ay = fmaf(w0, h.y, b.y);

        const int c0 = rowptr[node];
        const int cn = cnt[node];
        for (int e8 = 0; e8 < cn; e8 += 8) {
            const int4* q = (const int4*)(csr + c0 + e8);   // 16B-aligned (c0,e8 even)
            int4 q0 = q[0], q1 = q[1], q2 = q[2], q3 = q[3];
            float2 g0 = H2[(size_t)q0.x * 64 + lane];
            float2 g1 = H2[(size_t)q0.z * 64 + lane];
            float2 g2 = H2[(size_t)q1.x * 64 + lane];
            float2 g3 = H2[(size_t)q1.z * 64 + lane];
            float2 g4 = H2[(size_t)q2.x * 64 + lane];
            float2 g5 = H2[(size_t)q2.z * 64 + lane];
            float2 g6 = H2[(size_t)q3.x * 64 + lane];
            float2 g7 = H2[(size_t)q3.z * 64 + lane];
            float w0_ = __int_as_float(q0.y), w1_ = __int_as_float(q0.w);
            float w2_ = __int_as_float(q1.y), w3_ = __int_as_float(q1.w);
            float w4_ = __int_as_float(q2.y), w5_ = __int_as_float(q2.w);
            float w6_ = __int_as_float(q3.y), w7_ = __int_as_float(q3.w);
            ax = fmaf(w0_, g0.x, ax); ay = fmaf(w0_, g0.y, ay);
            ax = fmaf(w1_, g1.x, ax); ay = fmaf(w1_, g1.y, ay);
            ax = fmaf(w2_, g2.x, ax); ay = fmaf(w2_, g2.y, ay);
            ax = fmaf(w3_, g3.x, ax); ay = fmaf(w3_, g3.y, ay);
            ax = fmaf(w4_, g4.x, ax); ay = fmaf(w4_, g4.y, ay);
            ax = fmaf(w5_, g5.x, ax); ay = fmaf(w5_, g5.y, ay);
            ax = fmaf(w6_, g6.x, ax); ay = fmaf(w6_, g6.y, ay);
            ax = fmaf(w7_, g7.x, ax); ay = fmaf(w7_, g7.y, ay);
        }

        if (RELU) {
            ax = fmaxf(ax, 0.f);
            ay = fmaxf(ay, 0.f);
        }
        *(float2*)&out[(size_t)node * 128 + lane * 2] = make_float2(ax, ay);
    }
}

// ---------------- launch ----------------

extern "C" void kernel_launch(void* const* d_in, const int* in_sizes, int n_in,
                              void* d_out, int out_size, void* d_ws, size_t ws_size,
                              hipStream_t stream) {
    const float* x  = (const float*)d_in[0];
    const int*   ei = (const int*)d_in[1];
    const float* W1 = (const float*)d_in[2];
    const float* b1 = (const float*)d_in[3];
    const float* W2 = (const float*)d_in[4];
    const float* b2 = (const float*)d_in[5];
    const float* W3 = (const float*)d_in[6];
    const float* b3 = (const float*)d_in[7];
    float* out = (float*)d_out;

    const int N = N_NODES, E = N_EDGES;
    const int EP = E + 7 * N + 64;   // padded CSR capacity (8-padding worst case)
    const int* src = ei;       // edge_index[0]
    const int* dst = ei + E;   // edge_index[1]

    char* w = (char*)d_ws;
    auto alloc = [&](size_t bytes) -> void* {
        void* p = (void*)w;
        w += (bytes + 255) & ~(size_t)255;
        return p;
    };
    int*   cnt      = (int*)alloc((size_t)N * 4);
    int*   excl     = (int*)alloc((size_t)N * 4);
    int*   bsum     = (int*)alloc(4096);
    int*   rowptr   = (int*)alloc((size_t)N * 4);
    int*   fill     = (int*)alloc((size_t)N * 4);
    float* dinv     = (float*)alloc((size_t)N * 4);
    int2*  csr      = (int2*)alloc((size_t)EP * 8);
    float* P        = (float*)alloc((size_t)N * 128 * 4);
    float* Q        = out;  // ping-pong through d_out; fully rewritten by final layer

    const int nbN = (N + 255) / 256;   // 391
    const int nbE = (E + 255) / 256;
    const int nbP = (EP + 255) / 256;

    // CSR build (8-padded segments, zero-filled padding)
    k_zero_int<<<nbN, 256, 0, stream>>>(cnt, N);
    k_count<<<nbE, 256, 0, stream>>>(dst, cnt, E);
    k_scan_block<<<nbN, 256, 0, stream>>>(cnt, excl, bsum, N);
    k_scan_partials<<<1, 512, 0, stream>>>(bsum, nbN);
    k_finalize<<<nbN, 256, 0, stream>>>(excl, bsum, cnt, rowptr, fill, dinv, N);
    k_zero_csr<<<nbP, 256, 0, stream>>>(csr, EP);
    k_fill_edges<<<nbE, 256, 0, stream>>>(src, dst, dinv, fill, csr, E);

    const int gemm_grid = (N + 63) / 64;   // 1563
    const int agg_grid  = 2048;            // grid-stride, 4 waves/block

    // layer 1
    k_gemm<256><<<gemm_grid, 256, 0, stream>>>(x, W1, P, N);
    k_agg<true><<<agg_grid, 256, 0, stream>>>(P, rowptr, cnt, csr, dinv, b1, Q, N);
    // layer 2
    k_gemm<128><<<gemm_grid, 256, 0, stream>>>(Q, W2, P, N);
    k_agg<true><<<agg_grid, 256, 0, stream>>>(P, rowptr, cnt, csr, dinv, b2, Q, N);
    // layer 3
    k_gemm<128><<<gemm_grid, 256, 0, stream>>>(Q, W3, P, N);
    k_agg<false><<<agg_grid, 256, 0, stream>>>(P, rowptr, cnt, csr, dinv, b3, out, N);
}

// Round 4
// 549.276 us; speedup vs baseline: 1.6236x; 1.3190x over previous
//
#include <hip/hip_runtime.h>
#include <hip/hip_fp16.h>
#include <math.h>

// GCN 3-layer: h = relu(Agg(x@W1)+b1); h = relu(Agg(h@W2)+b2); out = Agg(h@W3)+b3
// Agg[i] = dinv[i]^2 * g[i] + sum_{e: dst=i} dinv[src]*dinv[i] * g[src]
// dinv = rsqrt(in_deg + 1)   (self-loop included)
// GEMM outputs (pre-aggregation activations) are stored fp16 to halve the
// random-gather traffic; accumulation stays f32.

#define N_NODES 100000
#define N_EDGES 1600000

// ---------------- preprocessing ----------------

__global__ __launch_bounds__(256) void k_zero_int(int* __restrict__ p, int n) {
    int i = blockIdx.x * 256 + threadIdx.x;
    if (i < n) p[i] = 0;
}

__global__ __launch_bounds__(256) void k_count(const int* __restrict__ dst, int* __restrict__ cnt, int E) {
    int e = blockIdx.x * 256 + threadIdx.x;
    if (e < E) atomicAdd(&cnt[dst[e]], 1);
}

// per-256-block exclusive scan (over 8-padded counts) + block sums
__global__ __launch_bounds__(256) void k_scan_block(const int* __restrict__ cnt, int* __restrict__ excl,
                                                    int* __restrict__ bsum, int n) {
    __shared__ int s[256];
    int i = blockIdx.x * 256 + threadIdx.x;
    int v = (i < n) ? ((cnt[i] + 7) & ~7) : 0;   // padded segment length
    s[threadIdx.x] = v;
    __syncthreads();
    #pragma unroll
    for (int off = 1; off < 256; off <<= 1) {
        int t = (threadIdx.x >= (unsigned)off) ? s[threadIdx.x - off] : 0;
        __syncthreads();
        s[threadIdx.x] += t;
        __syncthreads();
    }
    if (i < n) excl[i] = s[threadIdx.x] - v;
    if (threadIdx.x == 255) bsum[blockIdx.x] = s[255];
}

// single-block exclusive scan over block sums (nb <= 512)
__global__ __launch_bounds__(512) void k_scan_partials(int* __restrict__ bsum, int nb) {
    __shared__ int s[512];
    int tid = threadIdx.x;
    int v = (tid < nb) ? bsum[tid] : 0;
    s[tid] = v;
    __syncthreads();
    #pragma unroll
    for (int off = 1; off < 512; off <<= 1) {
        int t = (tid >= (unsigned)off) ? s[tid - off] : 0;
        __syncthreads();
        s[tid] += t;
        __syncthreads();
    }
    if (tid < nb) bsum[tid] = s[tid] - v;   // exclusive
}

__global__ __launch_bounds__(256) void k_finalize(const int* __restrict__ excl, const int* __restrict__ bsum,
                                                  const int* __restrict__ cnt, int* __restrict__ rowptr,
                                                  int* __restrict__ fill, float* __restrict__ dinv, int n) {
    int i = blockIdx.x * 256 + threadIdx.x;
    if (i < n) {
        int rp = excl[i] + bsum[i >> 8];
        rowptr[i] = rp;     // 8-aligned (scan of multiples of 8)
        fill[i]   = rp;
        dinv[i]   = rsqrtf((float)(cnt[i] + 1));  // +1 self loop; always > 0
    }
}

// zero paired csr so padding slots gather node 0 with weight 0
__global__ __launch_bounds__(256) void k_zero_csr(int2* __restrict__ csr, int n) {
    int i = blockIdx.x * 256 + threadIdx.x;
    if (i < n) csr[i] = make_int2(0, 0);
}

__global__ __launch_bounds__(256) void k_fill_edges(const int* __restrict__ src, const int* __restrict__ dst,
                                                    const float* __restrict__ dinv, int* __restrict__ fill,
                                                    int2* __restrict__ csr, int E) {
    int e = blockIdx.x * 256 + threadIdx.x;
    if (e < E) {
        int s = src[e], d = dst[e];
        int p = atomicAdd(&fill[d], 1);
        csr[p] = make_int2(s, __float_as_int(dinv[s] * dinv[d]));
    }
}

// ---------------- f32 GEMM: Y[n,128] = X[n,K] @ W[K,128], fp16 output ----------------
// BM=64, BN=128, BK=32, 256 threads, 8x4 micro-tile/thread. LDS 24 KB.

template <int K>
__global__ __launch_bounds__(256) void k_gemm(const float* __restrict__ X, const float* __restrict__ W,
                                              __half* __restrict__ Y, int n) {
    __shared__ float sX[64][32];    // 8 KB
    __shared__ float sW[32][128];   // 16 KB
    const int t    = threadIdx.x;
    const int row0 = blockIdx.x * 64;
    const int tn   = t & 31;   // cols 4*tn .. 4*tn+3
    const int tm   = t >> 5;   // rows 8*tm .. 8*tm+7

    float acc[8][4];
    #pragma unroll
    for (int i = 0; i < 8; ++i)
        #pragma unroll
        for (int j = 0; j < 4; ++j) acc[i][j] = 0.f;

    for (int kb = 0; kb < K; kb += 32) {
        // X tile: 64x32 floats = 512 float4, 2 per thread
        #pragma unroll
        for (int i = 0; i < 2; ++i) {
            int f  = t + i * 256;
            int r  = f >> 3;        // /8 float4-per-row
            int c4 = f & 7;
            int gr = row0 + r;
            float4 v = make_float4(0.f, 0.f, 0.f, 0.f);
            if (gr < n) v = *(const float4*)&X[(size_t)gr * K + kb + c4 * 4];
            *(float4*)&sX[r][c4 * 4] = v;
        }
        // W tile: 32x128 floats = 1024 float4, 4 per thread
        #pragma unroll
        for (int i = 0; i < 4; ++i) {
            int f  = t + i * 256;
            int r  = f >> 5;        // /32 float4-per-row
            int c4 = f & 31;
            *(float4*)&sW[r][c4 * 4] = *(const float4*)&W[(size_t)(kb + r) * 128 + c4 * 4];
        }
        __syncthreads();

        #pragma unroll
        for (int k4 = 0; k4 < 32; k4 += 4) {
            float4 bv[4];
            #pragma unroll
            for (int kk = 0; kk < 4; ++kk) bv[kk] = *(const float4*)&sW[k4 + kk][tn * 4];
            #pragma unroll
            for (int i = 0; i < 8; ++i) {
                float4 av = *(const float4*)&sX[tm * 8 + i][k4];
                #pragma unroll
                for (int j = 0; j < 4; ++j) {
                    float b0 = ((const float*)&bv[0])[j];
                    float b1 = ((const float*)&bv[1])[j];
                    float b2 = ((const float*)&bv[2])[j];
                    float b3 = ((const float*)&bv[3])[j];
                    acc[i][j] = fmaf(av.x, b0, acc[i][j]);
                    acc[i][j] = fmaf(av.y, b1, acc[i][j]);
                    acc[i][j] = fmaf(av.z, b2, acc[i][j]);
                    acc[i][j] = fmaf(av.w, b3, acc[i][j]);
                }
            }
        }
        __syncthreads();
    }

    #pragma unroll
    for (int i = 0; i < 8; ++i) {
        int gr = row0 + tm * 8 + i;
        if (gr < n) {
            __half2 h01 = __floats2half2_rn(acc[i][0], acc[i][1]);
            __half2 h23 = __floats2half2_rn(acc[i][2], acc[i][3]);
            uint2 v = make_uint2(*(unsigned int*)&h01, *(unsigned int*)&h23);
            *(uint2*)&Y[(size_t)gr * 128 + tn * 4] = v;   // 8 B aligned
        }
    }
}

// ---------------- aggregation (+ bias, + optional relu) ----------------
// one wave per node, grid-stride; lane holds 2 features (one uint = 2 halves,
// wave reads 256 B/row). CSR 8-padded, interleaved (src, norm_bits) int2.
// 8 independent row gathers issued per iteration (x2 unroll -> 16 in flight).

template <bool RELU>
__global__ __launch_bounds__(256) void k_agg(const __half* __restrict__ H, const int* __restrict__ rowptr,
                                             const int* __restrict__ cnt, const int2* __restrict__ csr,
                                             const float* __restrict__ dinv, const float* __restrict__ bias,
                                             float* __restrict__ out, int n) {
    const int lane  = threadIdx.x & 63;
    const int wave0 = (int)((blockIdx.x * 256 + threadIdx.x) >> 6);
    const int nwave = (int)((gridDim.x * 256) >> 6);
    const unsigned int* __restrict__ Hu = (const unsigned int*)H;   // 64 uints per row
    const float2 b = *(const float2*)&bias[lane * 2];

    for (int node = wave0; node < n; node += nwave) {
        float dv = dinv[node];
        unsigned int hu = Hu[(size_t)node * 64 + lane];
        float2 h = __half22float2(*(__half2*)&hu);
        float w0 = dv * dv;
        float ax = fmaf(w0, h.x, b.x);
        float ay = fmaf(w0, h.y, b.y);

        const int c0 = rowptr[node];
        const int cn = cnt[node];
        #pragma unroll 2
        for (int e8 = 0; e8 < cn; e8 += 8) {
            const int4* q = (const int4*)(csr + c0 + e8);   // 16B-aligned
            int4 q0 = q[0], q1 = q[1], q2 = q[2], q3 = q[3];
            unsigned int u0 = Hu[(size_t)q0.x * 64 + lane];
            unsigned int u1 = Hu[(size_t)q0.z * 64 + lane];
            unsigned int u2 = Hu[(size_t)q1.x * 64 + lane];
            unsigned int u3 = Hu[(size_t)q1.z * 64 + lane];
            unsigned int u4 = Hu[(size_t)q2.x * 64 + lane];
            unsigned int u5 = Hu[(size_t)q2.z * 64 + lane];
            unsigned int u6 = Hu[(size_t)q3.x * 64 + lane];
            unsigned int u7 = Hu[(size_t)q3.z * 64 + lane];
            float2 g0 = __half22float2(*(__half2*)&u0);
            float2 g1 = __half22float2(*(__half2*)&u1);
            float2 g2 = __half22float2(*(__half2*)&u2);
            float2 g3 = __half22float2(*(__half2*)&u3);
            float2 g4 = __half22float2(*(__half2*)&u4);
            float2 g5 = __half22float2(*(__half2*)&u5);
            float2 g6 = __half22float2(*(__half2*)&u6);
            float2 g7 = __half22float2(*(__half2*)&u7);
            float w0_ = __int_as_float(q0.y), w1_ = __int_as_float(q0.w);
            float w2_ = __int_as_float(q1.y), w3_ = __int_as_float(q1.w);
            float w4_ = __int_as_float(q2.y), w5_ = __int_as_float(q2.w);
            float w6_ = __int_as_float(q3.y), w7_ = __int_as_float(q3.w);
            ax = fmaf(w0_, g0.x, ax); ay = fmaf(w0_, g0.y, ay);
            ax = fmaf(w1_, g1.x, ax); ay = fmaf(w1_, g1.y, ay);
            ax = fmaf(w2_, g2.x, ax); ay = fmaf(w2_, g2.y, ay);
            ax = fmaf(w3_, g3.x, ax); ay = fmaf(w3_, g3.y, ay);
            ax = fmaf(w4_, g4.x, ax); ay = fmaf(w4_, g4.y, ay);
            ax = fmaf(w5_, g5.x, ax); ay = fmaf(w5_, g5.y, ay);
            ax = fmaf(w6_, g6.x, ax); ay = fmaf(w6_, g6.y, ay);
            ax = fmaf(w7_, g7.x, ax); ay = fmaf(w7_, g7.y, ay);
        }

        if (RELU) {
            ax = fmaxf(ax, 0.f);
            ay = fmaxf(ay, 0.f);
        }
        *(float2*)&out[(size_t)node * 128 + lane * 2] = make_float2(ax, ay);
    }
}

// ---------------- launch ----------------

extern "C" void kernel_launch(void* const* d_in, const int* in_sizes, int n_in,
                              void* d_out, int out_size, void* d_ws, size_t ws_size,
                              hipStream_t stream) {
    const float* x  = (const float*)d_in[0];
    const int*   ei = (const int*)d_in[1];
    const float* W1 = (const float*)d_in[2];
    const float* b1 = (const float*)d_in[3];
    const float* W2 = (const float*)d_in[4];
    const float* b2 = (const float*)d_in[5];
    const float* W3 = (const float*)d_in[6];
    const float* b3 = (const float*)d_in[7];
    float* out = (float*)d_out;

    const int N = N_NODES, E = N_EDGES;
    const int EP = E + 7 * N + 64;   // padded CSR capacity (8-padding worst case)
    const int* src = ei;       // edge_index[0]
    const int* dst = ei + E;   // edge_index[1]

    char* w = (char*)d_ws;
    auto alloc = [&](size_t bytes) -> void* {
        void* p = (void*)w;
        w += (bytes + 255) & ~(size_t)255;
        return p;
    };
    int*    cnt    = (int*)alloc((size_t)N * 4);
    int*    excl   = (int*)alloc((size_t)N * 4);
    int*    bsum   = (int*)alloc(4096);
    int*    rowptr = (int*)alloc((size_t)N * 4);
    int*    fill   = (int*)alloc((size_t)N * 4);
    float*  dinv   = (float*)alloc((size_t)N * 4);
    int2*   csr    = (int2*)alloc((size_t)EP * 8);
    __half* Ph     = (__half*)alloc((size_t)N * 128 * 2);   // fp16 activations
    float*  Q      = out;  // f32 ping-pong through d_out; fully rewritten by final layer

    const int nbN = (N + 255) / 256;   // 391
    const int nbE = (E + 255) / 256;
    const int nbP = (EP + 255) / 256;

    // CSR build (8-padded segments, zero-filled padding)
    k_zero_int<<<nbN, 256, 0, stream>>>(cnt, N);
    k_count<<<nbE, 256, 0, stream>>>(dst, cnt, E);
    k_scan_block<<<nbN, 256, 0, stream>>>(cnt, excl, bsum, N);
    k_scan_partials<<<1, 512, 0, stream>>>(bsum, nbN);
    k_finalize<<<nbN, 256, 0, stream>>>(excl, bsum, cnt, rowptr, fill, dinv, N);
    k_zero_csr<<<nbP, 256, 0, stream>>>(csr, EP);
    k_fill_edges<<<nbE, 256, 0, stream>>>(src, dst, dinv, fill, csr, E);

    const int gemm_grid = (N + 63) / 64;   // 1563
    const int agg_grid  = 2048;            // grid-stride, 4 waves/block

    // layer 1
    k_gemm<256><<<gemm_grid, 256, 0, stream>>>(x, W1, Ph, N);
    k_agg<true><<<agg_grid, 256, 0, stream>>>(Ph, rowptr, cnt, csr, dinv, b1, Q, N);
    // layer 2
    k_gemm<128><<<gemm_grid, 256, 0, stream>>>(Q, W2, Ph, N);
    k_agg<true><<<agg_grid, 256, 0, stream>>>(Ph, rowptr, cnt, csr, dinv, b2, Q, N);
    // layer 3
    k_gemm<128><<<gemm_grid, 256, 0, stream>>>(Q, W3, Ph, N);
    k_agg<false><<<agg_grid, 256, 0, stream>>>(Ph, rowptr, cnt, csr, dinv, b3, out, N);
}